// Round 12
// baseline (270.358 us; speedup 1.0000x reference)
//
#include <hip/hip_runtime.h>

#define DT 0.01f

// Native 4-float vector for nontemporal builtins (HIP's float4 is a class
// type, which __builtin_nontemporal_store rejects).
typedef float f32x4 __attribute__((ext_vector_type(4)));

// ---- Pass 1 (L=16): per-chunk local aggregate, zero initial state ----------
// Pure HBM read: keep maximum per-thread MLP (all 16 loads in flight).
__global__ __launch_bounds__(256) void fol_pass1_L16(
        const float* __restrict__ in, const float* __restrict__ tau,
        float* __restrict__ B, int N4) {
    const int chunk = blockIdx.y;
    const int ch4 = blockIdx.x * 256 + threadIdx.x;
    if (ch4 >= N4) return;

    const float4* p = reinterpret_cast<const float4*>(in) + (size_t)chunk * 16 * N4 + ch4;
    float4 x[16];
    #pragma unroll
    for (int t = 0; t < 16; ++t) x[t] = p[(size_t)t * N4];

    const float4 tv = reinterpret_cast<const float4*>(tau)[ch4];
    const float ax = DT / fmaxf(tv.x, DT), ay = DT / fmaxf(tv.y, DT),
                az = DT / fmaxf(tv.z, DT), aw = DT / fmaxf(tv.w, DT);
    const float qx = 1.f - ax, qy = 1.f - ay, qz = 1.f - az, qw = 1.f - aw;

    float sx = 0.f, sy = 0.f, sz = 0.f, sw = 0.f;
    #pragma unroll
    for (int t = 0; t < 16; ++t) {
        sx = fmaf(qx, sx, ax * x[t].x);
        sy = fmaf(qy, sy, ay * x[t].y);
        sz = fmaf(qz, sz, az * x[t].z);
        sw = fmaf(qw, sw, aw * x[t].w);
    }
    reinterpret_cast<float4*>(B)[(size_t)chunk * N4 + ch4] = make_float4(sx, sy, sz, sw);
}

// ---- Pass 2: sequential combine across chunks, software-pipelined ----------
// In-place B[c][n] (aggregate) -> S[c][n] (state entering chunk c). 32-deep MLP.
__global__ __launch_bounds__(256) void fol_pass2_pipe(
        const float* __restrict__ in, const float* __restrict__ tau,
        float* __restrict__ B, int N, int C, int L) {
    const int ch = blockIdx.x * 256 + threadIdx.x;
    if (ch >= N) return;
    const float a = DT / fmaxf(tau[ch], DT);
    const float q = 1.f - a;
    float qL = 1.f, b = q;
    int e = L;
    while (e) { if (e & 1) qL *= b; b *= b; e >>= 1; }

    float S = in[ch];  // s_0 = input[0]

    constexpr int BATCH = 32;
    float x[BATCH], xn[BATCH];
    #pragma unroll
    for (int j = 0; j < BATCH; ++j) x[j] = B[(size_t)j * N + ch];

    for (int cb = 0; cb < C; cb += BATCH) {
        const int nb = cb + BATCH;
        if (nb < C) {
            #pragma unroll
            for (int j = 0; j < BATCH; ++j) xn[j] = B[(size_t)(nb + j) * N + ch];
        }
        #pragma unroll
        for (int j = 0; j < BATCH; ++j) {
            B[(size_t)(cb + j) * N + ch] = S;     // publish chunk-entry state
            S = fmaf(qL, S, x[j]);                // advance one chunk
        }
        #pragma unroll
        for (int j = 0; j < BATCH; ++j) x[j] = xn[j];
    }
}

// ---- Pass 3 (L=16): rescan each chunk from its true start state ------------
// Mixed L3-read + HBM-nt-write: 2 batches of 8 rows. Halves live x[] VGPRs
// (~4 -> ~5-6 waves/SIMD) and starts the store stream after 8 rows instead
// of 16, improving read/write overlap across waves.
__global__ __launch_bounds__(256) void fol_pass3_L16(
        const float* __restrict__ in, const float* __restrict__ tau,
        const float* __restrict__ bias, const float* __restrict__ S,
        float* __restrict__ out, int N4) {
    const int chunk = blockIdx.y;
    const int ch4 = blockIdx.x * 256 + threadIdx.x;
    if (ch4 >= N4) return;

    const float4* p = reinterpret_cast<const float4*>(in) + (size_t)chunk * 16 * N4 + ch4;
    f32x4*       o = reinterpret_cast<f32x4*>(out)        + (size_t)chunk * 16 * N4 + ch4;

    // Batch 0 loads issued first (in flight while we set up parameters).
    float4 x[8];
    #pragma unroll
    for (int j = 0; j < 8; ++j) x[j] = p[(size_t)j * N4];

    const float4 tv = reinterpret_cast<const float4*>(tau)[ch4];
    const float4 bv = reinterpret_cast<const float4*>(bias)[ch4];
    const float ax = DT / fmaxf(tv.x, DT), ay = DT / fmaxf(tv.y, DT),
                az = DT / fmaxf(tv.z, DT), aw = DT / fmaxf(tv.w, DT);
    const float qx = 1.f - ax, qy = 1.f - ay, qz = 1.f - az, qw = 1.f - aw;

    const float4 sv = reinterpret_cast<const float4*>(S)[(size_t)chunk * N4 + ch4];
    float sx = sv.x, sy = sv.y, sz = sv.z, sw = sv.w;

    #pragma unroll
    for (int j = 0; j < 8; ++j) {
        sx = fmaf(qx, sx, ax * x[j].x);
        sy = fmaf(qy, sy, ay * x[j].y);
        sz = fmaf(qz, sz, az * x[j].z);
        sw = fmaf(qw, sw, aw * x[j].w);
        f32x4 ov; ov.x = sx + bv.x; ov.y = sy + bv.y; ov.z = sz + bv.z; ov.w = sw + bv.w;
        __builtin_nontemporal_store(ov, &o[(size_t)j * N4]);
    }

    // Batch 1.
    #pragma unroll
    for (int j = 0; j < 8; ++j) x[j] = p[(size_t)(8 + j) * N4];
    #pragma unroll
    for (int j = 0; j < 8; ++j) {
        sx = fmaf(qx, sx, ax * x[j].x);
        sy = fmaf(qy, sy, ay * x[j].y);
        sz = fmaf(qz, sz, az * x[j].z);
        sw = fmaf(qw, sw, aw * x[j].w);
        f32x4 ov; ov.x = sx + bv.x; ov.y = sy + bv.y; ov.z = sz + bv.z; ov.w = sw + bv.w;
        __builtin_nontemporal_store(ov, &o[(size_t)(8 + j) * N4]);
    }
}

// ---- Fallback: naive thread-per-channel scan (odd shapes only) -------------
__global__ void fol_naive(const float* __restrict__ in, const float* __restrict__ tau,
                          const float* __restrict__ bias, float* __restrict__ out,
                          int N, int T) {
    const int ch = blockIdx.x * blockDim.x + threadIdx.x;
    if (ch >= N) return;
    const float a = DT / fmaxf(tau[ch], DT);
    const float q = 1.f - a;
    const float b = bias[ch];
    float s = in[ch];
    for (int t = 0; t < T; ++t) {
        const float x = in[(size_t)t * N + ch];
        s = fmaf(q, s, a * x);
        out[(size_t)t * N + ch] = s + b;
    }
}

extern "C" void kernel_launch(void* const* d_in, const int* in_sizes, int n_in,
                              void* d_out, int out_size, void* d_ws, size_t ws_size,
                              hipStream_t stream) {
    const float* in   = (const float*)d_in[0];
    const float* tau  = (const float*)d_in[1];
    const float* bias = (const float*)d_in[2];
    float* out = (float*)d_out;
    float* B   = (float*)d_ws;

    const int N = in_sizes[1];
    const int T = in_sizes[0] / N;

    const bool vec_ok = (N % 4 == 0);

    // Proven path (R11: 268 µs total, ~95 µs of kernels): C=512 chunks, L=16.
    if (vec_ok && T == 8192 && ((size_t)512 * N * sizeof(float)) <= ws_size) {
        const int C = 512, L = 16, N4 = N / 4;
        const dim3 blk(256);
        const dim3 g13((N4 + 255) / 256, C);
        fol_pass1_L16<<<g13, blk, 0, stream>>>(in, tau, B, N4);
        fol_pass2_pipe<<<dim3((N + 255) / 256), blk, 0, stream>>>(in, tau, B, N, C, L);
        fol_pass3_L16<<<g13, blk, 0, stream>>>(in, tau, bias, B, out, N4);
        return;
    }

    fol_naive<<<dim3((N + 255) / 256), dim3(256), 0, stream>>>(in, tau, bias, out, N, T);
}